// Round 12
// baseline (3008.047 us; speedup 1.0000x reference)
//
#include <hip/hip_runtime.h>

#define M_DIM 65536
#define K_DIM 2048
#define N_DIM 1024
#define EPSV 1e-5f

typedef __bf16 bf16;
typedef bf16 bf16x8 __attribute__((ext_vector_type(8)));
typedef bf16 bf16x4 __attribute__((ext_vector_type(4)));
typedef float f32x4 __attribute__((ext_vector_type(4)));

// monotone float <-> uint encoding for atomicMin on float
__device__ inline unsigned fenc(float f) {
    unsigned u = __float_as_uint(f);
    return (u & 0x80000000u) ? ~u : (u | 0x80000000u);
}
__device__ inline float fdec(unsigned e) {
    unsigned u = (e & 0x80000000u) ? (e & 0x7fffffffu) : ~e;
    return __uint_as_float(u);
}

__device__ __forceinline__ void gload_lds16(const bf16* g, bf16* l) {
    __builtin_amdgcn_global_load_lds(
        (const __attribute__((address_space(1))) unsigned int*)g,
        (__attribute__((address_space(3))) unsigned int*)l, 16, 0, 0);
}

// fp32 -> bf16 conversion, vectorized
__global__ void cvt_kernel(const float* __restrict__ in, bf16* __restrict__ out, long n4) {
    long i = (long)blockIdx.x * blockDim.x + threadIdx.x;
    long stride = (long)gridDim.x * blockDim.x;
    for (; i < n4; i += stride) {
        float4 v = ((const float4*)in)[i];
        bf16x4 h;
        h[0] = (bf16)v.x; h[1] = (bf16)v.y; h[2] = (bf16)v.z; h[3] = (bf16)v.w;
        ((bf16x4*)out)[i] = h;
    }
}

// Stage one [256 rows][32 k] bf16 half-tile (16 KB): 512 threads x 2
// global_load_lds(16B). LDS dest LINEAR; XOR swizzle (granule ^= (row>>1)&3)
// applied to the GLOBAL source (both-sides involution). Conflict-free (R2: 0).
__device__ __forceinline__ void stage_half(const bf16* __restrict__ g0, int kbase,
                                           bf16* slot, int tid) {
#pragma unroll
    for (int i = 0; i < 2; ++i) {
        int gidx = i * 512 + tid;           // 16B granule id, 1024 per half-tile
        int row = gidx >> 2;                // 4 granules (64B) per row
        int gsw = (gidx & 3) ^ ((row >> 1) & 3);
        gload_lds16(g0 + (size_t)row * K_DIM + kbase + gsw * 8,
                    slot + (size_t)(i * 512 + (tid & 448)) * 8);  // wave-uniform base
    }
}

// LDS: 4 slots only — A[parity], B[parity] of [256][32] bf16 = 64 KiB total.
// => TWO blocks per CU (16 waves): the DS-service / barrier windows of one
// block are filled by the other block's MFMA (m97/m114 mechanism). All
// 256^2 variants so far had 128 KB => 1 block/CU => CU-wide idle windows.
#define ASL(P) (lds + (P) * 8192)
#define BSL(P) (lds + 16384 + (P) * 8192)

// 256x256 tile, BK=32 K-steps (64 steps); 8 waves (2Mx4N), per-wave 128x64
// (8x4 frags of 16x16x32, 32 MFMA per step as 2 thin phases of 16).
// Per step: GATE(vmcnt(0)+barrier; drains the 4 loads staged one full step
// earlier) -> 8 ds_read (A mh0 + B) -> stage A(t+1) -> MFMA mh0 ->
// 4 ds_read (A mh1) -> stage B(t+1) -> MFMA mh1. Ratio 12 reads : 32 MFMA
// per lane-step == R2's proven 3:1. Write-after-read: stage targets
// parity^1, last read in step t-1, whose reads completed before t-1's
// close barrier (lgkm before MFMA use); stage issues after the GATE
// barrier. Read-after-write: gated by vmcnt(0) at step top.
__global__ __launch_bounds__(512, 4)
void gemm_fused(const bf16* __restrict__ Xb, const bf16* __restrict__ Wb,
                const float* __restrict__ gnw, const float* __restrict__ gnb,
                unsigned* __restrict__ rowmin) {
    extern __shared__ __align__(16) bf16 lds[];  // 64 KiB dynamic

    const int tid = threadIdx.x;
    const int wave = tid >> 6, lane = tid & 63;
    const int wr = wave >> 2, wc = wave & 3;     // 2 x 4 wave grid
    const int q = lane >> 4, r = lane & 15;

    // T1: bijective XCD-chunked block swizzle (1024 blocks % 8 == 0)
    const int bid = blockIdx.x;
    const int swz = (bid & 7) * 128 + (bid >> 3);
    const int bx = swz & 3, by = swz >> 2;
    const int brow = by * 256, bcol = bx * 256;

    const bf16* Arow = Xb + (size_t)brow * K_DIM;
    const bf16* Brow = Wb + (size_t)bcol * K_DIM;

    // per-lane LDS read offsets (bf16 units); swizzle term (row>>1)&3 == (r>>1)&3
    const int gswr = (r >> 1) & 3;
    const int aoff = (wr * 128 + r) * 32 + (q ^ gswr) * 8;
    const int boff = (wc * 64 + r) * 32 + (q ^ gswr) * 8;

    f32x4 acc[8][4];
#pragma unroll
    for (int m = 0; m < 8; ++m)
#pragma unroll
        for (int n = 0; n < 4; ++n) acc[m][n] = 0.0f;

    bf16x8 af[4], bfr[4];

#define GATE do {                                                 \
        asm volatile("s_waitcnt vmcnt(0)" ::: "memory");          \
        __builtin_amdgcn_s_barrier();                             \
        asm volatile("" ::: "memory");                            \
    } while (0)

#define READ_A(P, MH) {                                                           \
        _Pragma("unroll") for (int m = 0; m < 4; ++m)                             \
            af[m] = *(const bf16x8*)(ASL(P) + aoff + ((MH) * 4 + m) * 512);       \
    }
#define READ_B(P) {                                                               \
        _Pragma("unroll") for (int n = 0; n < 4; ++n)                             \
            bfr[n] = *(const bf16x8*)(BSL(P) + boff + n * 512);                   \
    }

#define MFMA_PH(MH) do {                                                          \
        __builtin_amdgcn_s_barrier();                                             \
        __builtin_amdgcn_s_setprio(1);                                            \
        _Pragma("unroll") for (int m = 0; m < 4; ++m)                             \
            _Pragma("unroll") for (int n = 0; n < 4; ++n)                         \
                acc[(MH) * 4 + m][n] = __builtin_amdgcn_mfma_f32_16x16x32_bf16(   \
                    af[m], bfr[n], acc[(MH) * 4 + m][n], 0, 0, 0);                \
        __builtin_amdgcn_s_setprio(0);                                            \
        __builtin_amdgcn_s_barrier();                                             \
    } while (0)

    // One K-step of 32, parity P; stages step T+1 into parity^1.
#define STEP(P, T) do {                                                           \
        const int kn = (((T) + 1) & 63) * 32;                                     \
        GATE;                                                                     \
        READ_A(P, 0); READ_B(P);                                                  \
        stage_half(Arow, kn, ASL(1 - (P)), tid);                                  \
        MFMA_PH(0);                                                               \
        READ_A(P, 1);                                                             \
        stage_half(Brow, kn, BSL(1 - (P)), tid);                                  \
        MFMA_PH(1);                                                               \
    } while (0)

    // ---- prologue: stage step 0 (A+B = 4 loads/thread); first GATE eats
    // the one-time HBM latency.
    stage_half(Arow, 0, ASL(0), tid);
    stage_half(Brow, 0, BSL(0), tid);

    // ---- main loop: 64 K-steps (K=2048, BK=32), parity-unrolled ----
    for (int t = 0; t < 64; t += 2) {
        STEP(0, t);
        STEP(1, t + 1);
    }

    // ---- fused epilogue: GroupNorm (group == wave's 64-col span) + row min ----
    float gw[4], gb[4];
#pragma unroll
    for (int n = 0; n < 4; ++n) {
        int col = bcol + wc * 64 + n * 16 + r;
        gw[n] = gnw[col];
        gb[n] = gnb[col];
    }
#pragma unroll
    for (int m = 0; m < 8; ++m) {
#pragma unroll
        for (int j = 0; j < 4; ++j) {
            float s = 0.f, ss = 0.f;
#pragma unroll
            for (int n = 0; n < 4; ++n) {
                float v = acc[m][n][j];
                s += v; ss += v * v;
            }
#pragma unroll
            for (int d = 1; d < 16; d <<= 1) {
                s += __shfl_xor(s, d);
                ss += __shfl_xor(ss, d);
            }
            float mean = s * (1.f / 64.f);
            float var = ss * (1.f / 64.f) - mean * mean;
            float rstd = rsqrtf(var + EPSV);
            float mn = 3.4e38f;
#pragma unroll
            for (int n = 0; n < 4; ++n) {
                float y = (acc[m][n][j] - mean) * rstd * gw[n] + gb[n];
                mn = fminf(mn, y);
            }
#pragma unroll
            for (int d = 1; d < 16; d <<= 1) mn = fminf(mn, __shfl_xor(mn, d));
            if (r == 0)
                atomicMin(&rowmin[brow + wr * 128 + m * 16 + q * 4 + j], fenc(mn));
        }
    }
}

// out[m][n] = dec(rowmin[m]) + bias[n]
__global__ void bcast_kernel(const unsigned* __restrict__ rowmin,
                             const float* __restrict__ bias,
                             float* __restrict__ out) {
    const long total4 = (long)M_DIM * N_DIM / 4;
    long i = (long)blockIdx.x * blockDim.x + threadIdx.x;
    long stride = (long)gridDim.x * blockDim.x;
    for (; i < total4; i += stride) {
        int mrow = (int)(i >> 8);  // N/4 = 256 float4 per row
        int n4 = (int)(i & 255);
        float rm = fdec(rowmin[mrow]);
        float4 b = ((const float4*)bias)[n4];
        float4 o;
        o.x = rm + b.x; o.y = rm + b.y; o.z = rm + b.z; o.w = rm + b.w;
        ((float4*)out)[i] = o;
    }
}

extern "C" void kernel_launch(void* const* d_in, const int* in_sizes, int n_in,
                              void* d_out, int out_size, void* d_ws, size_t ws_size,
                              hipStream_t stream) {
    const float* x = (const float*)d_in[0];
    const float* w = (const float*)d_in[1];
    const float* gnw = (const float*)d_in[2];
    const float* gnb = (const float*)d_in[3];
    const float* bias = (const float*)d_in[4];

    unsigned char* ws = (unsigned char*)d_ws;
    unsigned* rowmin = (unsigned*)ws;                          // 256 KB
    bf16* wb = (bf16*)(ws + (size_t)M_DIM * 4);                // 4 MB
    bf16* xb = (bf16*)(ws + (size_t)M_DIM * 4 + (size_t)N_DIM * K_DIM * 2);  // 256 MB

    hipFuncSetAttribute((const void*)gemm_fused,
                        hipFuncAttributeMaxDynamicSharedMemorySize, 65536);

    hipMemsetAsync(rowmin, 0xFF, (size_t)M_DIM * 4, stream);   // +inf in encoding
    cvt_kernel<<<512, 256, 0, stream>>>(w, wb, (long)N_DIM * K_DIM / 4);
    cvt_kernel<<<4096, 256, 0, stream>>>(x, xb, (long)M_DIM * K_DIM / 4);

    gemm_fused<<<dim3(1024), 512, 65536, stream>>>(xb, wb, gnw, gnb, rowmin);

    bcast_kernel<<<2048, 256, 0, stream>>>(rowmin, bias, (float*)d_out);
}

// Round 13
// 525.146 us; speedup vs baseline: 5.7280x; 5.7280x over previous
//
#include <hip/hip_runtime.h>

#define M_DIM 65536
#define K_DIM 2048
#define N_DIM 1024
#define EPSV 1e-5f

typedef __bf16 bf16;
typedef bf16 bf16x8 __attribute__((ext_vector_type(8)));
typedef bf16 bf16x4 __attribute__((ext_vector_type(4)));
typedef float f32x4 __attribute__((ext_vector_type(4)));

// monotone float <-> uint encoding for atomicMin on float
__device__ inline unsigned fenc(float f) {
    unsigned u = __float_as_uint(f);
    return (u & 0x80000000u) ? ~u : (u | 0x80000000u);
}
__device__ inline float fdec(unsigned e) {
    unsigned u = (e & 0x80000000u) ? (e & 0x7fffffffu) : ~e;
    return __uint_as_float(u);
}

__device__ __forceinline__ void gload_lds16(const bf16* g, bf16* l) {
    __builtin_amdgcn_global_load_lds(
        (const __attribute__((address_space(1))) unsigned int*)g,
        (__attribute__((address_space(3))) unsigned int*)l, 16, 0, 0);
}

// fp32 -> bf16 conversion, vectorized
__global__ void cvt_kernel(const float* __restrict__ in, bf16* __restrict__ out, long n4) {
    long i = (long)blockIdx.x * blockDim.x + threadIdx.x;
    long stride = (long)gridDim.x * blockDim.x;
    for (; i < n4; i += stride) {
        float4 v = ((const float4*)in)[i];
        bf16x4 h;
        h[0] = (bf16)v.x; h[1] = (bf16)v.y; h[2] = (bf16)v.z; h[3] = (bf16)v.w;
        ((bf16x4*)out)[i] = h;
    }
}

// R1 structure + swizzle: 128x128 tile, BK=64, 4 waves (2x2), single-
// buffered 2-barrier loop, 32 KB static LDS -> 3-4 blocks/CU (43% occ in
// R1) so cross-block wave overlap pipelines DS vs MFMA implicitly (m97/
// m114 mechanism). NEW vs R1: XOR swizzle kills R1's 1.0e8 bank-conflict
// cycles. [128][64] bf16 rows = 128 B = 8 granules of 16 B; row stride
// wraps all 32 banks, so unswizzled column reads are 16-way conflicted.
// Store: slot (row,g) <- global granule g^(row&7) (source-side swizzle,
// LDS dest stays linear per gload_lds HW rule). Read: granule
// (kk/8+q)^(r&7) -> involution returns global granule kk/8+q. Resulting
// read density = 8 lanes per 4-bank group = R2's measured-zero pattern.
__global__ void gemm_fused(const bf16* __restrict__ Xb, const bf16* __restrict__ Wb,
                           const float* __restrict__ gnw, const float* __restrict__ gnb,
                           unsigned* __restrict__ rowmin) {
    __shared__ __align__(16) bf16 As[128][64];
    __shared__ __align__(16) bf16 Bs[128][64];

    const int tid = threadIdx.x;
    const int wave = tid >> 6, lane = tid & 63;
    const int wr = wave >> 1, wc = wave & 1;   // 2 x 2 wave grid
    const int q = lane >> 4, r = lane & 15;

    // T1: bijective XCD-chunked swizzle (4096 blocks % 8 == 0); chunk of
    // 512 consecutive swz per XCD = 64 by x 8 bx -> A-panel L2 reuse.
    const int bid = blockIdx.x;
    const int swz = (bid & 7) * 512 + (bid >> 3);
    const int bx = swz & 7, by = swz >> 3;
    const int brow = by * 128, bcol = bx * 128;

    const bf16* Arow = Xb + (size_t)brow * K_DIM;
    const bf16* Brow = Wb + (size_t)bcol * K_DIM;

    f32x4 acc[4][4];
#pragma unroll
    for (int m = 0; m < 4; ++m)
#pragma unroll
        for (int n = 0; n < 4; ++n) acc[m][n] = 0.0f;

    // read-side swizzled granule offsets (bf16 units), per kk half:
    // granule gd = kk/8 + q, slot = gd ^ (r&7), byte = slot*16
    const int r7 = r & 7;
    const int ga0 = ((0 + q) ^ r7) * 8;   // kk = 0
    const int ga1 = ((4 + q) ^ r7) * 8;   // kk = 32
    const int arow_l = wr * 64 + r;       // + m*16
    const int brow_l = wc * 64 + r;       // + n*16

    for (int kt = 0; kt < K_DIM / 64; ++kt) {
        const int k0 = kt * 64;
        // stage A and B tiles: 1024 granules each, 4 iters x 256 threads;
        // source-side swizzle g ^= (row&7); LDS dest linear (wave base +
        // lane*16 enforced by HW).
#pragma unroll
        for (int i = 0; i < 4; ++i) {
            int chunk = i * 256 + tid;
            int row = chunk >> 3, g = chunk & 7;
            int gsw = g ^ (row & 7);
            gload_lds16(Arow + (size_t)row * K_DIM + k0 + gsw * 8,
                        &As[0][0] + (size_t)(i * 256 + (tid & 192)) * 8);
        }
#pragma unroll
        for (int i = 0; i < 4; ++i) {
            int chunk = i * 256 + tid;
            int row = chunk >> 3, g = chunk & 7;
            int gsw = g ^ (row & 7);
            gload_lds16(Brow + (size_t)row * K_DIM + k0 + gsw * 8,
                        &Bs[0][0] + (size_t)(i * 256 + (tid & 192)) * 8);
        }
        __syncthreads();  // drains vmcnt+lgkm before barrier (compiler)

#pragma unroll
        for (int kk = 0; kk < 2; ++kk) {
            const int ga = kk ? ga1 : ga0;
            bf16x8 a[4], b[4];
#pragma unroll
            for (int m = 0; m < 4; ++m)
                a[m] = *(const bf16x8*)(&As[0][0] + (arow_l + m * 16) * 64 + ga);
#pragma unroll
            for (int n = 0; n < 4; ++n)
                b[n] = *(const bf16x8*)(&Bs[0][0] + (brow_l + n * 16) * 64 + ga);
#pragma unroll
            for (int m = 0; m < 4; ++m)
#pragma unroll
                for (int n = 0; n < 4; ++n)
                    acc[m][n] = __builtin_amdgcn_mfma_f32_16x16x32_bf16(
                        a[m], b[n], acc[m][n], 0, 0, 0);
        }
        __syncthreads();
    }

    // ---- fused epilogue: GroupNorm (group == wave's 64-col span) + row min ----
    float gw[4], gb[4];
#pragma unroll
    for (int n = 0; n < 4; ++n) {
        int col = bcol + wc * 64 + n * 16 + r;
        gw[n] = gnw[col];
        gb[n] = gnb[col];
    }
#pragma unroll
    for (int m = 0; m < 4; ++m) {
#pragma unroll
        for (int j = 0; j < 4; ++j) {
            float s = 0.f, ss = 0.f;
#pragma unroll
            for (int n = 0; n < 4; ++n) {
                float v = acc[m][n][j];
                s += v; ss += v * v;
            }
#pragma unroll
            for (int d = 1; d < 16; d <<= 1) {
                s += __shfl_xor(s, d);
                ss += __shfl_xor(ss, d);
            }
            float mean = s * (1.f / 64.f);
            float var = ss * (1.f / 64.f) - mean * mean;
            float rstd = rsqrtf(var + EPSV);
            float mn = 3.4e38f;
#pragma unroll
            for (int n = 0; n < 4; ++n) {
                float y = (acc[m][n][j] - mean) * rstd * gw[n] + gb[n];
                mn = fminf(mn, y);
            }
#pragma unroll
            for (int d = 1; d < 16; d <<= 1) mn = fminf(mn, __shfl_xor(mn, d));
            if (r == 0)
                atomicMin(&rowmin[brow + wr * 64 + m * 16 + q * 4 + j], fenc(mn));
        }
    }
}

// out[m][n] = dec(rowmin[m]) + bias[n]
__global__ void bcast_kernel(const unsigned* __restrict__ rowmin,
                             const float* __restrict__ bias,
                             float* __restrict__ out) {
    const long total4 = (long)M_DIM * N_DIM / 4;
    long i = (long)blockIdx.x * blockDim.x + threadIdx.x;
    long stride = (long)gridDim.x * blockDim.x;
    for (; i < total4; i += stride) {
        int mrow = (int)(i >> 8);  // N/4 = 256 float4 per row
        int n4 = (int)(i & 255);
        float rm = fdec(rowmin[mrow]);
        float4 b = ((const float4*)bias)[n4];
        float4 o;
        o.x = rm + b.x; o.y = rm + b.y; o.z = rm + b.z; o.w = rm + b.w;
        ((float4*)out)[i] = o;
    }
}

extern "C" void kernel_launch(void* const* d_in, const int* in_sizes, int n_in,
                              void* d_out, int out_size, void* d_ws, size_t ws_size,
                              hipStream_t stream) {
    const float* x = (const float*)d_in[0];
    const float* w = (const float*)d_in[1];
    const float* gnw = (const float*)d_in[2];
    const float* gnb = (const float*)d_in[3];
    const float* bias = (const float*)d_in[4];

    unsigned char* ws = (unsigned char*)d_ws;
    unsigned* rowmin = (unsigned*)ws;                          // 256 KB
    bf16* wb = (bf16*)(ws + (size_t)M_DIM * 4);                // 4 MB
    bf16* xb = (bf16*)(ws + (size_t)M_DIM * 4 + (size_t)N_DIM * K_DIM * 2);  // 256 MB

    hipMemsetAsync(rowmin, 0xFF, (size_t)M_DIM * 4, stream);   // +inf in encoding
    cvt_kernel<<<512, 256, 0, stream>>>(w, wb, (long)N_DIM * K_DIM / 4);
    cvt_kernel<<<4096, 256, 0, stream>>>(x, xb, (long)M_DIM * K_DIM / 4);

    gemm_fused<<<dim3(4096), 256, 0, stream>>>(xb, wb, gnw, gnb, rowmin);

    bcast_kernel<<<2048, 256, 0, stream>>>(rowmin, bias, (float*)d_out);
}

// Round 15
// 504.442 us; speedup vs baseline: 5.9631x; 1.0410x over previous
//
#include <hip/hip_runtime.h>

#define M_DIM 65536
#define K_DIM 2048
#define N_DIM 1024
#define EPSV 1e-5f

typedef __bf16 bf16;
typedef bf16 bf16x8 __attribute__((ext_vector_type(8)));
typedef bf16 bf16x4 __attribute__((ext_vector_type(4)));
typedef float f32x4 __attribute__((ext_vector_type(4)));

// monotone float <-> uint encoding for atomicMin on float
__device__ inline unsigned fenc(float f) {
    unsigned u = __float_as_uint(f);
    return (u & 0x80000000u) ? ~u : (u | 0x80000000u);
}
__device__ inline float fdec(unsigned e) {
    unsigned u = (e & 0x80000000u) ? (e & 0x7fffffffu) : ~e;
    return __uint_as_float(u);
}

__device__ __forceinline__ void gload_lds16(const bf16* g, bf16* l) {
    __builtin_amdgcn_global_load_lds(
        (const __attribute__((address_space(1))) unsigned int*)g,
        (__attribute__((address_space(3))) unsigned int*)l, 16, 0, 0);
}

// fp32 -> bf16 conversion (W only: 4 MB, ~2 us)
__global__ void cvt_kernel(const float* __restrict__ in, bf16* __restrict__ out, long n4) {
    long i = (long)blockIdx.x * blockDim.x + threadIdx.x;
    long stride = (long)gridDim.x * blockDim.x;
    for (; i < n4; i += stride) {
        f32x4 v = ((const f32x4*)in)[i];
        bf16x4 h;
        h[0] = (bf16)v[0]; h[1] = (bf16)v[1]; h[2] = (bf16)v[2]; h[3] = (bf16)v[3];
        ((bf16x4*)out)[i] = h;
    }
}

// R13 structure (m97-recipe: 128x128, BK=64, 4 waves, 2-barrier loop,
// 32 KB LDS -> 3-4 blocks/CU, cross-block DS/MFMA overlap, conflict-free
// XOR swizzle, XCD-chunked block swizzle) + NEW: A is staged DIRECTLY from
// FP32 x inside the loop (8 coalesced float4 loads -> pack bf16 -> 4
// ds_write_b128 at write-side-swizzled addresses). Eliminates the 120 us
// cvt_x pass and its 512 MB HBM round-trip; the multi-block overlap that
// hides gload_lds latency also hides the cvt VALU + va-wait (the R5
// failure was trying this in a 1-block/CU lockstep structure).
// Bank balance of the swizzled ds_write: each 16B slot gets exactly 8
// lanes -> minimum-cycle 1KB/wave, same as DMA's linear pattern.
__global__ void gemm_fused(const float* __restrict__ X, const bf16* __restrict__ Wb,
                           const float* __restrict__ gnw, const float* __restrict__ gnb,
                           unsigned* __restrict__ rowmin) {
    __shared__ __align__(16) bf16 As[128][64];
    __shared__ __align__(16) bf16 Bs[128][64];

    const int tid = threadIdx.x;
    const int wave = tid >> 6, lane = tid & 63;
    const int wr = wave >> 1, wc = wave & 1;   // 2 x 2 wave grid
    const int q = lane >> 4, r = lane & 15;

    // T1: bijective XCD-chunked swizzle (4096 blocks % 8 == 0); chunk of
    // 512 consecutive swz per XCD = 64 by x 8 bx; bx fastest -> the fp32
    // A-panel (1 MB) is read from HBM once per by and re-served by L2.
    const int bid = blockIdx.x;
    const int swz = (bid & 7) * 512 + (bid >> 3);
    const int bx = swz & 7, by = swz >> 3;
    const int brow = by * 128, bcol = bx * 128;

    const float* Arowf = X + (size_t)brow * K_DIM;
    const bf16* Brow = Wb + (size_t)bcol * K_DIM;

    f32x4 acc[4][4];
#pragma unroll
    for (int m = 0; m < 4; ++m)
#pragma unroll
        for (int n = 0; n < 4; ++n) acc[m][n] = 0.0f;

    // read-side swizzled granule offsets (bf16 units), per kk half:
    // granule gd = kk/8 + q, slot = gd ^ (r&7), byte = slot*16
    const int r7 = r & 7;
    const int ga0 = ((0 + q) ^ r7) * 8;   // kk = 0
    const int ga1 = ((4 + q) ^ r7) * 8;   // kk = 32
    const int arow_l = wr * 64 + r;       // + m*16
    const int brow_l = wc * 64 + r;       // + n*16

    for (int kt = 0; kt < K_DIM / 64; ++kt) {
        const int k0 = kt * 64;

        // ---- A: reg-stage fp32 -> bf16 with write-side swizzle ----
        // granule gi = j*256 + tid; row = gi>>3, g = gi&7 (8 granules/row);
        // source = floats [k0+8g .. k0+8g+7] of row (coalesced 32B/lane).
        f32x4 va[8];
#pragma unroll
        for (int j = 0; j < 4; ++j) {
            int gi = j * 256 + tid;
            int row = gi >> 3, g = gi & 7;
            const float* src = Arowf + (size_t)row * K_DIM + k0 + g * 8;
            va[2 * j]     = *(const f32x4*)(src);
            va[2 * j + 1] = *(const f32x4*)(src + 4);
        }
        // ---- B: proven gload_lds + source-side swizzle ----
#pragma unroll
        for (int i = 0; i < 4; ++i) {
            int chunk = i * 256 + tid;
            int row = chunk >> 3, g = chunk & 7;
            int gsw = g ^ (row & 7);
            gload_lds16(Brow + (size_t)row * K_DIM + k0 + gsw * 8,
                        &Bs[0][0] + (size_t)(i * 256 + (tid & 192)) * 8);
        }
        // ---- A: convert + swizzled ds_write_b128 (waits va; B DMA overlaps) ----
#pragma unroll
        for (int j = 0; j < 4; ++j) {
            int gi = j * 256 + tid;
            int row = gi >> 3, g = gi & 7;
            bf16x8 h;
            h[0] = (bf16)va[2 * j][0];     h[1] = (bf16)va[2 * j][1];
            h[2] = (bf16)va[2 * j][2];     h[3] = (bf16)va[2 * j][3];
            h[4] = (bf16)va[2 * j + 1][0]; h[5] = (bf16)va[2 * j + 1][1];
            h[6] = (bf16)va[2 * j + 1][2]; h[7] = (bf16)va[2 * j + 1][3];
            *(bf16x8*)(&As[0][0] + (size_t)row * 64 + (size_t)(g ^ (row & 7)) * 8) = h;
        }
        __syncthreads();  // compiler drains lgkm (A writes) + vmcnt (B DMA)

#pragma unroll
        for (int kk = 0; kk < 2; ++kk) {
            const int ga = kk ? ga1 : ga0;
            bf16x8 a[4], b[4];
#pragma unroll
            for (int m = 0; m < 4; ++m)
                a[m] = *(const bf16x8*)(&As[0][0] + (arow_l + m * 16) * 64 + ga);
#pragma unroll
            for (int n = 0; n < 4; ++n)
                b[n] = *(const bf16x8*)(&Bs[0][0] + (brow_l + n * 16) * 64 + ga);
#pragma unroll
            for (int m = 0; m < 4; ++m)
#pragma unroll
                for (int n = 0; n < 4; ++n)
                    acc[m][n] = __builtin_amdgcn_mfma_f32_16x16x32_bf16(
                        a[m], b[n], acc[m][n], 0, 0, 0);
        }
        __syncthreads();
    }

    // ---- fused epilogue: GroupNorm (group == wave's 64-col span) + row min ----
    float gw[4], gb[4];
#pragma unroll
    for (int n = 0; n < 4; ++n) {
        int col = bcol + wc * 64 + n * 16 + r;
        gw[n] = gnw[col];
        gb[n] = gnb[col];
    }
#pragma unroll
    for (int m = 0; m < 4; ++m) {
#pragma unroll
        for (int j = 0; j < 4; ++j) {
            float s = 0.f, ss = 0.f;
#pragma unroll
            for (int n = 0; n < 4; ++n) {
                float v = acc[m][n][j];
                s += v; ss += v * v;
            }
#pragma unroll
            for (int d = 1; d < 16; d <<= 1) {
                s += __shfl_xor(s, d);
                ss += __shfl_xor(ss, d);
            }
            float mean = s * (1.f / 64.f);
            float var = ss * (1.f / 64.f) - mean * mean;
            float rstd = rsqrtf(var + EPSV);
            float mn = 3.4e38f;
#pragma unroll
            for (int n = 0; n < 4; ++n) {
                float y = (acc[m][n][j] - mean) * rstd * gw[n] + gb[n];
                mn = fminf(mn, y);
            }
#pragma unroll
            for (int d = 1; d < 16; d <<= 1) mn = fminf(mn, __shfl_xor(mn, d));
            if (r == 0)
                atomicMin(&rowmin[brow + wr * 64 + m * 16 + q * 4 + j], fenc(mn));
        }
    }
}

// out[m][n] = dec(rowmin[m]) + bias[n]
__global__ void bcast_kernel(const unsigned* __restrict__ rowmin,
                             const float* __restrict__ bias,
                             float* __restrict__ out) {
    const long total4 = (long)M_DIM * N_DIM / 4;
    long i = (long)blockIdx.x * blockDim.x + threadIdx.x;
    long stride = (long)gridDim.x * blockDim.x;
    for (; i < total4; i += stride) {
        int mrow = (int)(i >> 8);  // N/4 = 256 float4 per row
        int n4 = (int)(i & 255);
        float rm = fdec(rowmin[mrow]);
        f32x4 b = ((const f32x4*)bias)[n4];
        f32x4 o;
        o[0] = rm + b[0]; o[1] = rm + b[1]; o[2] = rm + b[2]; o[3] = rm + b[3];
        ((f32x4*)out)[i] = o;
    }
}

extern "C" void kernel_launch(void* const* d_in, const int* in_sizes, int n_in,
                              void* d_out, int out_size, void* d_ws, size_t ws_size,
                              hipStream_t stream) {
    const float* x = (const float*)d_in[0];
    const float* w = (const float*)d_in[1];
    const float* gnw = (const float*)d_in[2];
    const float* gnb = (const float*)d_in[3];
    const float* bias = (const float*)d_in[4];

    unsigned char* ws = (unsigned char*)d_ws;
    unsigned* rowmin = (unsigned*)ws;                          // 256 KB
    bf16* wb = (bf16*)(ws + (size_t)M_DIM * 4);                // 4 MB

    (void)hipMemsetAsync(rowmin, 0xFF, (size_t)M_DIM * 4, stream);  // +inf in encoding
    cvt_kernel<<<512, 256, 0, stream>>>(w, wb, (long)N_DIM * K_DIM / 4);

    gemm_fused<<<dim3(4096), 256, 0, stream>>>(x, wb, gnw, gnb, rowmin);

    bcast_kernel<<<2048, 256, 0, stream>>>(rowmin, bias, (float*)d_out);
}